// Round 5
// baseline (224.768 us; speedup 1.0000x reference)
//
#include <hip/hip_runtime.h>

#define NB 32
#define NN 1024
#define DINR 144

typedef __attribute__((ext_vector_type(4))) float f4;
typedef __attribute__((ext_vector_type(8))) short s8;

// ws float offsets
#define OFF_A   (0u)
#define OFF_B0  (1u*NB*64*NN)
#define OFF_B1  (2u*NB*64*NN)
#define OFF_C   (3u*NB*64*NN)
#define OFF_UPA (4u*NB*64*NN)
#define OFF_UPB (OFF_UPA + NB*32*1024u)
#define OFF_NS  (OFF_UPB + NB*32*1024u)

// ---------------------------------------------------------------------------
// k_init
//  blocks [0,1024): b=blk>>5, ct=blk&31 (32-col slab):
//    stage x rows 0..79 + E in LDS; A = E@x[16:48] (row-major, coalesced wb),
//    B0 = E@x[48:80] (col-major), U0 partial chunk = (A-B0)@X^T (masked n<1008)
//  blocks [1024,1536): nstar[b][m] = argmax_{n<1008} X[:,m]·X[:,n]  (bf16 MFMA)
// ---------------------------------------------------------------------------
__global__ __launch_bounds__(256) void k_init(
    const float* __restrict__ x, const float* __restrict__ emb,
    float* __restrict__ A, float* __restrict__ Bt,
    float* __restrict__ Up, int* __restrict__ nstar)
{
  __shared__ union {
    unsigned int XT[NN * 8];                 // 32768 B (argmax part)
    struct {
      float xs[80 * 33];                     // 10560 B
      float es[512 * 4];                     // 8192 B (f4, swizzled)
      float as[64 * 33];                     // 8448 B
    } d;
  } sm;
  int t = threadIdx.x;
  if (blockIdx.x < 1024) {
    int b = blockIdx.x >> 5;
    int ct = blockIdx.x & 31;
    int n0 = ct * 32;
    const float* xb = x + (size_t)b * DINR * NN;
    for (int idx = t; idx < 80 * 32; idx += 256) {
      int row = idx >> 5, col = idx & 31;
      sm.d.xs[row * 33 + col] = xb[row * NN + n0 + col];
    }
    f4* es4 = reinterpret_cast<f4*>(sm.d.es);
    const f4* E4g = reinterpret_cast<const f4*>(emb);
    for (int fj = t; fj < 512; fj += 256) {
      int j = fj >> 3, cc = fj & 7;
      es4[j * 8 + ((cc ^ (j >> 3)) & 7)] = E4g[fj];
    }
    __syncthreads();
    int c = t >> 3, g = t & 7;
    int n = n0 + c;
    float a[8], bb[8];
    float xa[32];
    #pragma unroll
    for (int cc = 0; cc < 32; cc++) xa[cc] = sm.d.xs[(16 + cc) * 33 + c];
    #pragma unroll
    for (int jj = 0; jj < 8; jj++) {
      int j = g * 8 + jj;
      float acc = 0.f;
      #pragma unroll
      for (int cc = 0; cc < 8; cc++) {
        f4 e = es4[j * 8 + ((cc ^ g) & 7)];
        acc += e[0]*xa[4*cc] + e[1]*xa[4*cc+1] + e[2]*xa[4*cc+2] + e[3]*xa[4*cc+3];
      }
      a[jj] = acc;
    }
    #pragma unroll
    for (int cc = 0; cc < 32; cc++) xa[cc] = sm.d.xs[(48 + cc) * 33 + c];
    #pragma unroll
    for (int jj = 0; jj < 8; jj++) {
      int j = g * 8 + jj;
      float acc = 0.f;
      #pragma unroll
      for (int cc = 0; cc < 8; cc++) {
        f4 e = es4[j * 8 + ((cc ^ g) & 7)];
        acc += e[0]*xa[4*cc] + e[1]*xa[4*cc+1] + e[2]*xa[4*cc+2] + e[3]*xa[4*cc+3];
      }
      bb[jj] = acc;
    }
    // B0 col-major
    f4 v0 = {bb[0], bb[1], bb[2], bb[3]};
    f4 v1 = {bb[4], bb[5], bb[6], bb[7]};
    f4* Bb = reinterpret_cast<f4*>(Bt + ((size_t)b * NN + n) * 64 + g * 8);
    Bb[0] = v0; Bb[1] = v1;
    // stage A, coalesced writeback
    #pragma unroll
    for (int jj = 0; jj < 8; jj++) sm.d.as[(g * 8 + jj) * 33 + c] = a[jj];
    __syncthreads();
    float* Ab = A + (size_t)b * 64 * NN;
    for (int idx = t; idx < 2048; idx += 256) {
      int row = idx >> 5, col = idx & 31;
      Ab[row * NN + n0 + col] = sm.d.as[row * 33 + col];
    }
    __syncthreads();
    // w = (A - B0) masked -> as (in place per (j,c))
    bool live = (n < 1008);
    #pragma unroll
    for (int jj = 0; jj < 8; jj++)
      sm.d.as[(g * 8 + jj) * 33 + c] = live ? (a[jj] - bb[jj]) : 0.f;
    __syncthreads();
    // U0 chunk: Up[b][ct][j][i] = sum_c w[j][c] * X[i][c]
    float* upb = Up + ((size_t)(b * 32 + ct)) * 1024;
    for (int idx = t; idx < 1024; idx += 256) {
      int j = idx >> 4, i = idx & 15;
      float s = 0.f;
      #pragma unroll
      for (int cc = 0; cc < 32; cc++) s += sm.d.as[j * 33 + cc] * sm.d.xs[i * 33 + cc];
      upb[idx] = s;
    }
  } else {
    int a = blockIdx.x - 1024;
    int b = a >> 4;
    int mg = a & 15;
    const float* xb = x + (size_t)b * DINR * NN;
    #pragma unroll
    for (int rep = 0; rep < 4; rep++) {
      int n = t + (rep << 8);
      unsigned int pk[8];
      #pragma unroll
      for (int h = 0; h < 8; h++) {
        unsigned int u0 = __float_as_uint(xb[(2*h) * NN + n]);
        unsigned int u1 = __float_as_uint(xb[(2*h+1) * NN + n]);
        pk[h] = (u0 >> 16) | (u1 & 0xFFFF0000u);
      }
      #pragma unroll
      for (int h = 0; h < 8; h++) sm.XT[n * 8 + h] = pk[h];
    }
    __syncthreads();
    int w = t >> 6;
    int lane = t & 63;
    int r = lane & 15;
    int g = lane >> 4;
    int mt = mg * 64 + w * 16;
    s8 zero8 = {0,0,0,0,0,0,0,0};
    s8 afrag = zero8;
    if (g < 2) afrag = *reinterpret_cast<const s8*>(&sm.XT[(mt + r) * 8 + g * 4]);
    float bestv[4];
    int besti[4];
    #pragma unroll
    for (int j = 0; j < 4; j++) { bestv[j] = -3.4e38f; besti[j] = 0x7FFFFFFF; }
    for (int nt = 0; nt < 63; nt++) {
      s8 bfrag = zero8;
      if (g < 2) bfrag = *reinterpret_cast<const s8*>(&sm.XT[(nt*16 + r) * 8 + g * 4]);
      f4 acc = {0.f, 0.f, 0.f, 0.f};
      acc = __builtin_amdgcn_mfma_f32_16x16x32_bf16(afrag, bfrag, acc, 0, 0, 0);
      int n = nt * 16 + r;
      #pragma unroll
      for (int j = 0; j < 4; j++) {
        float v = acc[j];
        bool better = (v > bestv[j]) || (v == bestv[j] && n < besti[j]);
        if (better) { bestv[j] = v; besti[j] = n; }
      }
    }
    #pragma unroll
    for (int s = 1; s < 16; s <<= 1) {
      #pragma unroll
      for (int j = 0; j < 4; j++) {
        float ov = __shfl_xor(bestv[j], s, 64);
        int   oi = __shfl_xor(besti[j], s, 64);
        bool better = (ov > bestv[j]) || (ov == bestv[j] && oi < besti[j]);
        if (better) { bestv[j] = ov; besti[j] = oi; }
      }
    }
    if (r == 0) {
      #pragma unroll
      for (int j = 0; j < 4; j++)
        nstar[b * NN + mt + g * 4 + j] = besti[j];
    }
  }
}

// ---------------------------------------------------------------------------
// k_update (layer l): combine 32 Up chunks (apply alpha_l);
//   C[:,m] += (kp/M) U @ X[:,m];  logits = E^T C'; p = softmax(logits);
//   if !last: B_out[:,m] = B[:,m] - B[:,nstar]/M + E p ; Up_next chunk
//   if last : write logits + predictions, skip C/B writeback
// grid 1024 = 32 b x 32 m-tiles of 32 cols; c=t>>3 (col), g=t&7 (j-octet)
// ---------------------------------------------------------------------------
__global__ __launch_bounds__(256) void k_update(
    const float* __restrict__ x, const float* __restrict__ emb,
    const float* __restrict__ kpp, const float* __restrict__ alpha, int l,
    const float* __restrict__ Upin, float* __restrict__ Upout,
    const int* __restrict__ nstar, const float* __restrict__ Agl,
    const float* __restrict__ Cin, size_t cbs, float* __restrict__ Cout,
    const float* __restrict__ Bin, float* __restrict__ Bout,
    int last, float* __restrict__ out)
{
  __shared__ float Us[1024];       // swizzled combined U
  __shared__ float Ess[2048];      // E as f4[512], swizzled
  __shared__ float Xs[16 * 33];
  __shared__ float Cs[64 * 33];
  __shared__ float As[64 * 33];    // A slab; reused in-place for w
  int t = threadIdx.x;
  int b = blockIdx.x >> 5;
  int mt = blockIdx.x & 31;
  int n0 = mt * 32;
  // combine U chunks, apply alpha_l
  for (int idx = t; idx < 1024; idx += 256) {
    const float* up = Upin + (size_t)b * 32 * 1024 + idx;
    float s = 0.f;
    #pragma unroll 8
    for (int ch = 0; ch < 32; ch++) s += up[ch * 1024];
    s *= alpha[l * 64 + (idx >> 4)];
    int j = idx >> 4, i = idx & 15;
    Us[j * 16 + ((((i >> 2) ^ (j >> 3)) & 3) << 2) + (i & 3)] = s;
  }
  f4* es4 = reinterpret_cast<f4*>(Ess);
  const f4* E4g = reinterpret_cast<const f4*>(emb);
  for (int fj = t; fj < 512; fj += 256) {
    int j = fj >> 3, cc = fj & 7;
    es4[j * 8 + ((cc ^ (j >> 3)) & 7)] = E4g[fj];
  }
  const float* xb = x + (size_t)b * DINR * NN;
  for (int idx = t; idx < 512; idx += 256) {
    int r = idx >> 5, cl = idx & 31;
    Xs[r * 33 + cl] = xb[r * NN + n0 + cl];
  }
  for (int idx = t; idx < 2048; idx += 256) {
    int r = idx >> 5, cl = idx & 31;
    Cs[r * 33 + cl] = Cin[(size_t)b * cbs + r * NN + n0 + cl];
  }
  if (!last) {
    const float* Ab = Agl + (size_t)b * 64 * NN;
    for (int idx = t; idx < 2048; idx += 256) {
      int r = idx >> 5, cl = idx & 31;
      As[r * 33 + cl] = Ab[r * NN + n0 + cl];
    }
  }
  __syncthreads();
  int c = t >> 3, g = t & 7;
  int m = n0 + c;
  float X[16];
  #pragma unroll
  for (int i = 0; i < 16; i++) X[i] = Xs[i * 33 + c];
  float sc = kpp[0] * (1.0f / 1008.0f);
  float lg[32];
  #pragma unroll
  for (int k = 0; k < 32; k++) lg[k] = 0.f;
  const f4* U4 = reinterpret_cast<const f4*>(Us);
  #pragma unroll
  for (int jj = 0; jj < 8; jj++) {
    int j = g * 8 + jj;
    float d = 0.f;
    #pragma unroll
    for (int ii = 0; ii < 4; ii++) {
      f4 u = U4[j * 4 + ((ii ^ g) & 3)];
      d += u[0]*X[4*ii] + u[1]*X[4*ii+1] + u[2]*X[4*ii+2] + u[3]*X[4*ii+3];
    }
    float cn = Cs[j * 33 + c] + sc * d;
    Cs[j * 33 + c] = cn;
    #pragma unroll
    for (int cc = 0; cc < 8; cc++) {
      f4 e = es4[j * 8 + ((cc ^ g) & 7)];
      lg[4*cc+0] += cn * e[0]; lg[4*cc+1] += cn * e[1];
      lg[4*cc+2] += cn * e[2]; lg[4*cc+3] += cn * e[3];
    }
  }
  __syncthreads();
  if (!last) {
    float* Cb = Cout + (size_t)b * 64 * NN;
    for (int idx = t; idx < 2048; idx += 256) {
      int r = idx >> 5, cl = idx & 31;
      Cb[r * NN + n0 + cl] = Cs[r * 33 + cl];
    }
  }
  // reduce logits across the 8 g-lanes
  #pragma unroll
  for (int s = 1; s < 8; s <<= 1) {
    #pragma unroll
    for (int k = 0; k < 32; k++) lg[k] += __shfl_xor(lg[k], s, 64);
  }
  #define QUAD(gg) (f4){lg[4*(gg)], lg[4*(gg)+1], lg[4*(gg)+2], lg[4*(gg)+3]}
  f4 vlog;
  if (last) {
    switch (g) {
      case 0: vlog = QUAD(0); break;  case 1: vlog = QUAD(1); break;
      case 2: vlog = QUAD(2); break;  case 3: vlog = QUAD(3); break;
      case 4: vlog = QUAD(4); break;  case 5: vlog = QUAD(5); break;
      case 6: vlog = QUAD(6); break;  default: vlog = QUAD(7); break;
    }
  }
  float mx = lg[0];
  #pragma unroll
  for (int k = 1; k < 32; k++) mx = fmaxf(mx, lg[k]);
  float ssum = 0.f;
  #pragma unroll
  for (int k = 0; k < 32; k++) { lg[k] = __expf(lg[k] - mx); ssum += lg[k]; }
  float inv = 1.0f / ssum;
  #pragma unroll
  for (int k = 0; k < 32; k++) lg[k] *= inv;
  if (last) {
    f4 vpred;
    switch (g) {
      case 0: vpred = QUAD(0); break;  case 1: vpred = QUAD(1); break;
      case 2: vpred = QUAD(2); break;  case 3: vpred = QUAD(3); break;
      case 4: vpred = QUAD(4); break;  case 5: vpred = QUAD(5); break;
      case 6: vpred = QUAD(6); break;  default: vpred = QUAD(7); break;
    }
    float* lo = out + ((size_t)b * NN + m) * 32 + g * 4;
    float* po = lo + (size_t)NB * NN * 32;
    *reinterpret_cast<f4*>(lo) = vlog;
    *reinterpret_cast<f4*>(po) = vpred;
  }
  #undef QUAD
  if (!last) {
    // B update rows g*8..g*8+7 of column m
    int nst = nstar[b * NN + m];
    const f4* BC = reinterpret_cast<const f4*>(Bin + ((size_t)b * NN + m) * 64 + g * 8);
    const f4* BG = reinterpret_cast<const f4*>(Bin + ((size_t)b * NN + nst) * 64 + g * 8);
    f4* BO = reinterpret_cast<f4*>(Bout + ((size_t)b * NN + m) * 64 + g * 8);
    const float invM = 1.0f / 1008.0f;
    float vv[8];
    #pragma unroll
    for (int jg = 0; jg < 2; jg++) {
      f4 bc4 = BC[jg];
      f4 bg4 = BG[jg];
      f4 vo;
      #pragma unroll
      for (int k = 0; k < 4; k++) {
        int j = g * 8 + jg * 4 + k;
        float v = bc4[k] - bg4[k] * invM;
        #pragma unroll
        for (int cc = 0; cc < 8; cc++) {
          f4 e = es4[j * 8 + ((cc ^ g) & 7)];
          v += e[0]*lg[4*cc] + e[1]*lg[4*cc+1] + e[2]*lg[4*cc+2] + e[3]*lg[4*cc+3];
        }
        vo[k] = v;
        vv[jg * 4 + k] = v;
      }
      BO[jg] = vo;
    }
    // w = A - B_out (masked) into As in place
    bool live = (m < 1008);
    #pragma unroll
    for (int jj = 0; jj < 8; jj++) {
      float wv = As[(g * 8 + jj) * 33 + c] - vv[jj];
      As[(g * 8 + jj) * 33 + c] = live ? wv : 0.f;
    }
    __syncthreads();
    // Up_next chunk
    float* upb = Upout + ((size_t)(b * 32 + mt)) * 1024;
    for (int idx = t; idx < 1024; idx += 256) {
      int j = idx >> 4, i = idx & 15;
      float s = 0.f;
      #pragma unroll
      for (int cc = 0; cc < 32; cc++) s += As[j * 33 + cc] * Xs[i * 33 + cc];
      upb[idx] = s;
    }
  }
}

extern "C" void kernel_launch(void* const* d_in, const int* in_sizes, int n_in,
                              void* d_out, int out_size, void* d_ws, size_t ws_size,
                              hipStream_t stream)
{
  const float* x     = (const float*)d_in[0];
  const float* alpha = (const float*)d_in[1];
  const float* kp    = (const float*)d_in[2];
  const float* emb   = (const float*)d_in[3];
  float* ws = (float*)d_ws;
  float* A   = ws + OFF_A;
  float* B0  = ws + OFF_B0;
  float* B1  = ws + OFF_B1;
  float* C   = ws + OFF_C;
  float* UpA = ws + OFF_UPA;
  float* UpB = ws + OFF_UPB;
  int*   ns  = (int*)(ws + OFF_NS);
  float* out = (float*)d_out;

  k_init<<<1536, 256, 0, stream>>>(x, emb, A, B0, UpA, ns);
  // layer 0: Cin = x[80:144] (batch stride DINR*NN), B0 -> B1, UpA -> UpB
  k_update<<<1024, 256, 0, stream>>>(x, emb, kp, alpha, 0, UpA, UpB, ns, A,
                                     x + 80 * NN, (size_t)DINR * NN, C,
                                     B0, B1, 0, out);
  // layer 1: C in/out, B1 -> B0, UpB -> UpA
  k_update<<<1024, 256, 0, stream>>>(x, emb, kp, alpha, 1, UpB, UpA, ns, A,
                                     C, (size_t)64 * NN, C,
                                     B1, B0, 0, out);
  // layer 2 (last): outputs only
  k_update<<<1024, 256, 0, stream>>>(x, emb, kp, alpha, 2, UpA, UpB, ns, A,
                                     C, (size_t)64 * NN, C,
                                     B0, B1, 1, out);
}

// Round 6
// 161.168 us; speedup vs baseline: 1.3946x; 1.3946x over previous
//
#include <hip/hip_runtime.h>

#define NB 32
#define NN 1024
#define DINR 144

typedef __attribute__((ext_vector_type(4))) float f4;
typedef __attribute__((ext_vector_type(8))) short s8;

// ws float offsets
#define OFF_B0  (0u)
#define OFF_B1  (1u*NB*64*NN)
#define OFF_C   (2u*NB*64*NN)
#define OFF_UPA (3u*NB*64*NN)                 // B-part partials (ping)
#define OFF_UPB (OFF_UPA + NB*32*1024u)       // B-part partials (pong)
#define OFF_UPC (OFF_UPB + NB*32*1024u)       // A-part partials (static)
#define OFF_UC  (OFF_UPC + NB*32*1024u)       // combined U (per layer)
#define OFF_NS  (OFF_UC + NB*1024u)

// ---------------------------------------------------------------------------
// k_init
//  blocks [0,1024): b=blk>>5, ct=blk&31 (32-col slab):
//    stage x rows 0..79 + E in LDS; a = E@x[16:48], b0 = E@x[48:80];
//    write B0 (col-major); UpC chunk = a@X^T, UpB chunk = b0@X^T (masked n<1008)
//  blocks [1024,1536): nstar[b][m] = argmax_{n<1008} X[:,m]·X[:,n]  (bf16 MFMA)
// ---------------------------------------------------------------------------
__global__ __launch_bounds__(256) void k_init(
    const float* __restrict__ x, const float* __restrict__ emb,
    float* __restrict__ Bt, float* __restrict__ UpC, float* __restrict__ UpB,
    int* __restrict__ nstar)
{
  __shared__ union {
    unsigned int XT[NN * 8];                 // 32768 B (argmax part)
    struct {
      float xs[80 * 33];                     // 10560 B
      float es[512 * 4];                     // 8192 B (f4, swizzled)
      float as[64 * 33];                     // 8448 B
    } d;
  } sm;
  int t = threadIdx.x;
  if (blockIdx.x < 1024) {
    int b = blockIdx.x >> 5;
    int ct = blockIdx.x & 31;
    int n0 = ct * 32;
    const float* xb = x + (size_t)b * DINR * NN;
    for (int idx = t; idx < 80 * 32; idx += 256) {
      int row = idx >> 5, col = idx & 31;
      sm.d.xs[row * 33 + col] = xb[row * NN + n0 + col];
    }
    f4* es4 = reinterpret_cast<f4*>(sm.d.es);
    const f4* E4g = reinterpret_cast<const f4*>(emb);
    for (int fj = t; fj < 512; fj += 256) {
      int j = fj >> 3, cc = fj & 7;
      es4[j * 8 + ((cc ^ (j >> 3)) & 7)] = E4g[fj];
    }
    __syncthreads();
    int c = t >> 3, g = t & 7;
    int n = n0 + c;
    bool live = (n < 1008);
    float a[8], bb[8];
    float xa[32];
    #pragma unroll
    for (int cc = 0; cc < 32; cc++) xa[cc] = sm.d.xs[(16 + cc) * 33 + c];
    #pragma unroll
    for (int jj = 0; jj < 8; jj++) {
      int j = g * 8 + jj;
      float acc = 0.f;
      #pragma unroll
      for (int cc = 0; cc < 8; cc++) {
        f4 e = es4[j * 8 + ((cc ^ g) & 7)];
        acc += e[0]*xa[4*cc] + e[1]*xa[4*cc+1] + e[2]*xa[4*cc+2] + e[3]*xa[4*cc+3];
      }
      a[jj] = acc;
    }
    #pragma unroll
    for (int cc = 0; cc < 32; cc++) xa[cc] = sm.d.xs[(48 + cc) * 33 + c];
    #pragma unroll
    for (int jj = 0; jj < 8; jj++) {
      int j = g * 8 + jj;
      float acc = 0.f;
      #pragma unroll
      for (int cc = 0; cc < 8; cc++) {
        f4 e = es4[j * 8 + ((cc ^ g) & 7)];
        acc += e[0]*xa[4*cc] + e[1]*xa[4*cc+1] + e[2]*xa[4*cc+2] + e[3]*xa[4*cc+3];
      }
      bb[jj] = acc;
    }
    // B0 col-major
    f4 v0 = {bb[0], bb[1], bb[2], bb[3]};
    f4 v1 = {bb[4], bb[5], bb[6], bb[7]};
    f4* Bb = reinterpret_cast<f4*>(Bt + ((size_t)b * NN + n) * 64 + g * 8);
    Bb[0] = v0; Bb[1] = v1;
    // UpC chunk from a
    #pragma unroll
    for (int jj = 0; jj < 8; jj++)
      sm.d.as[(g * 8 + jj) * 33 + c] = live ? a[jj] : 0.f;
    __syncthreads();
    float* upc = UpC + ((size_t)(b * 32 + ct)) * 1024;
    for (int idx = t; idx < 1024; idx += 256) {
      int j = idx >> 4, i = idx & 15;
      float s = 0.f;
      #pragma unroll
      for (int cc = 0; cc < 32; cc++) s += sm.d.as[j * 33 + cc] * sm.d.xs[i * 33 + cc];
      upc[idx] = s;
    }
    __syncthreads();
    // UpB chunk from bb
    #pragma unroll
    for (int jj = 0; jj < 8; jj++)
      sm.d.as[(g * 8 + jj) * 33 + c] = live ? bb[jj] : 0.f;
    __syncthreads();
    float* upb = UpB + ((size_t)(b * 32 + ct)) * 1024;
    for (int idx = t; idx < 1024; idx += 256) {
      int j = idx >> 4, i = idx & 15;
      float s = 0.f;
      #pragma unroll
      for (int cc = 0; cc < 32; cc++) s += sm.d.as[j * 33 + cc] * sm.d.xs[i * 33 + cc];
      upb[idx] = s;
    }
  } else {
    int a = blockIdx.x - 1024;
    int b = a >> 4;
    int mg = a & 15;
    const float* xb = x + (size_t)b * DINR * NN;
    #pragma unroll
    for (int rep = 0; rep < 4; rep++) {
      int n = t + (rep << 8);
      unsigned int pk[8];
      #pragma unroll
      for (int h = 0; h < 8; h++) {
        unsigned int u0 = __float_as_uint(xb[(2*h) * NN + n]);
        unsigned int u1 = __float_as_uint(xb[(2*h+1) * NN + n]);
        pk[h] = (u0 >> 16) | (u1 & 0xFFFF0000u);
      }
      #pragma unroll
      for (int h = 0; h < 8; h++) sm.XT[n * 8 + h] = pk[h];
    }
    __syncthreads();
    int w = t >> 6;
    int lane = t & 63;
    int r = lane & 15;
    int g = lane >> 4;
    int mt = mg * 64 + w * 16;
    s8 zero8 = {0,0,0,0,0,0,0,0};
    s8 afrag = zero8;
    if (g < 2) afrag = *reinterpret_cast<const s8*>(&sm.XT[(mt + r) * 8 + g * 4]);
    float bestv[4];
    int besti[4];
    #pragma unroll
    for (int j = 0; j < 4; j++) { bestv[j] = -3.4e38f; besti[j] = 0x7FFFFFFF; }
    for (int nt = 0; nt < 63; nt++) {
      s8 bfrag = zero8;
      if (g < 2) bfrag = *reinterpret_cast<const s8*>(&sm.XT[(nt*16 + r) * 8 + g * 4]);
      f4 acc = {0.f, 0.f, 0.f, 0.f};
      acc = __builtin_amdgcn_mfma_f32_16x16x32_bf16(afrag, bfrag, acc, 0, 0, 0);
      int n = nt * 16 + r;
      #pragma unroll
      for (int j = 0; j < 4; j++) {
        float v = acc[j];
        bool better = (v > bestv[j]) || (v == bestv[j] && n < besti[j]);
        if (better) { bestv[j] = v; besti[j] = n; }
      }
    }
    #pragma unroll
    for (int s = 1; s < 16; s <<= 1) {
      #pragma unroll
      for (int j = 0; j < 4; j++) {
        float ov = __shfl_xor(bestv[j], s, 64);
        int   oi = __shfl_xor(besti[j], s, 64);
        bool better = (ov > bestv[j]) || (ov == bestv[j] && oi < besti[j]);
        if (better) { bestv[j] = ov; besti[j] = oi; }
      }
    }
    if (r == 0) {
      #pragma unroll
      for (int j = 0; j < 4; j++)
        nstar[b * NN + mt + g * 4 + j] = besti[j];
    }
  }
}

// ---------------------------------------------------------------------------
// k_comb: Uc[b][j][i] = alpha[l][j] * (sum_ch UpC - sum_ch UpB)
// grid 128 = 32 b x 4 quarters; thread sums 32+32 chunk values
// ---------------------------------------------------------------------------
__global__ __launch_bounds__(256) void k_comb(
    const float* __restrict__ UpC, const float* __restrict__ UpB,
    const float* __restrict__ alpha, int l, float* __restrict__ Uc)
{
  int b = blockIdx.x >> 2;
  int idx = ((blockIdx.x & 3) << 8) + threadIdx.x;
  const float* pc = UpC + (size_t)b * 32 * 1024 + idx;
  const float* pb = UpB + (size_t)b * 32 * 1024 + idx;
  float sa = 0.f, sb = 0.f;
  #pragma unroll 8
  for (int ch = 0; ch < 32; ch++) {
    sa += pc[ch * 1024];
    sb += pb[ch * 1024];
  }
  Uc[(size_t)b * 1024 + idx] = alpha[l * 64 + (idx >> 4)] * (sa - sb);
}

// ---------------------------------------------------------------------------
// k_update (layer l): C[:,m] += (kp/M) U @ X[:,m]; logits = E^T C';
//   p = softmax(logits);
//   if !last: B_out[:,m] = B[:,m] - B[:,nstar]/M + E p ; UpB_next chunk
//   if last : write logits + predictions only
// grid 1024 = 32 b x 32 m-tiles of 32 cols; c=t>>3 (col), g=t&7 (j-octet)
// ---------------------------------------------------------------------------
__global__ __launch_bounds__(256) void k_update(
    const float* __restrict__ x, const float* __restrict__ emb,
    const float* __restrict__ kpp, const float* __restrict__ Uc,
    const int* __restrict__ nstar,
    const float* __restrict__ Cin, size_t cbs, float* __restrict__ Cout,
    const float* __restrict__ Bin, float* __restrict__ Bout,
    float* __restrict__ Upout, int last, float* __restrict__ out)
{
  __shared__ float Us[1024];       // swizzled combined U
  __shared__ float Ess[2048];      // E as f4[512], swizzled
  __shared__ float Xs[16 * 33];
  __shared__ float Cs[64 * 33];    // C' tile; reused for w after writeback
  int t = threadIdx.x;
  int b = blockIdx.x >> 5;
  int mt = blockIdx.x & 31;
  int n0 = mt * 32;
  // stage combined U (swizzled)
  for (int idx = t; idx < 1024; idx += 256) {
    float s = Uc[(size_t)b * 1024 + idx];
    int j = idx >> 4, i = idx & 15;
    Us[j * 16 + ((((i >> 2) ^ (j >> 3)) & 3) << 2) + (i & 3)] = s;
  }
  f4* es4 = reinterpret_cast<f4*>(Ess);
  const f4* E4g = reinterpret_cast<const f4*>(emb);
  for (int fj = t; fj < 512; fj += 256) {
    int j = fj >> 3, cc = fj & 7;
    es4[j * 8 + ((cc ^ (j >> 3)) & 7)] = E4g[fj];
  }
  const float* xb = x + (size_t)b * DINR * NN;
  for (int idx = t; idx < 512; idx += 256) {
    int r = idx >> 5, cl = idx & 31;
    Xs[r * 33 + cl] = xb[r * NN + n0 + cl];
  }
  for (int idx = t; idx < 2048; idx += 256) {
    int r = idx >> 5, cl = idx & 31;
    Cs[r * 33 + cl] = Cin[(size_t)b * cbs + r * NN + n0 + cl];
  }
  __syncthreads();
  int c = t >> 3, g = t & 7;
  int m = n0 + c;
  float X[16];
  #pragma unroll
  for (int i = 0; i < 16; i++) X[i] = Xs[i * 33 + c];
  float sc = kpp[0] * (1.0f / 1008.0f);
  float lg[32];
  #pragma unroll
  for (int k = 0; k < 32; k++) lg[k] = 0.f;
  const f4* U4 = reinterpret_cast<const f4*>(Us);
  #pragma unroll
  for (int jj = 0; jj < 8; jj++) {
    int j = g * 8 + jj;
    float d = 0.f;
    #pragma unroll
    for (int ii = 0; ii < 4; ii++) {
      f4 u = U4[j * 4 + ((ii ^ g) & 3)];
      d += u[0]*X[4*ii] + u[1]*X[4*ii+1] + u[2]*X[4*ii+2] + u[3]*X[4*ii+3];
    }
    float cn = Cs[j * 33 + c] + sc * d;
    Cs[j * 33 + c] = cn;          // unique owner per (j,c) slot
    #pragma unroll
    for (int cc = 0; cc < 8; cc++) {
      f4 e = es4[j * 8 + ((cc ^ g) & 7)];
      lg[4*cc+0] += cn * e[0]; lg[4*cc+1] += cn * e[1];
      lg[4*cc+2] += cn * e[2]; lg[4*cc+3] += cn * e[3];
    }
  }
  if (!last) {
    __syncthreads();
    float* Cb = Cout + (size_t)b * 64 * NN;
    for (int idx = t; idx < 2048; idx += 256) {
      int r = idx >> 5, cl = idx & 31;
      Cb[r * NN + n0 + cl] = Cs[r * 33 + cl];
    }
    __syncthreads();   // Cs free for reuse after this point
  }
  // reduce logits across the 8 g-lanes
  #pragma unroll
  for (int s = 1; s < 8; s <<= 1) {
    #pragma unroll
    for (int k = 0; k < 32; k++) lg[k] += __shfl_xor(lg[k], s, 64);
  }
  #define QUAD(gg) (f4){lg[4*(gg)], lg[4*(gg)+1], lg[4*(gg)+2], lg[4*(gg)+3]}
  f4 vlog;
  if (last) {
    switch (g) {
      case 0: vlog = QUAD(0); break;  case 1: vlog = QUAD(1); break;
      case 2: vlog = QUAD(2); break;  case 3: vlog = QUAD(3); break;
      case 4: vlog = QUAD(4); break;  case 5: vlog = QUAD(5); break;
      case 6: vlog = QUAD(6); break;  default: vlog = QUAD(7); break;
    }
  }
  float mx = lg[0];
  #pragma unroll
  for (int k = 1; k < 32; k++) mx = fmaxf(mx, lg[k]);
  float ssum = 0.f;
  #pragma unroll
  for (int k = 0; k < 32; k++) { lg[k] = __expf(lg[k] - mx); ssum += lg[k]; }
  float inv = 1.0f / ssum;
  #pragma unroll
  for (int k = 0; k < 32; k++) lg[k] *= inv;
  if (last) {
    f4 vpred;
    switch (g) {
      case 0: vpred = QUAD(0); break;  case 1: vpred = QUAD(1); break;
      case 2: vpred = QUAD(2); break;  case 3: vpred = QUAD(3); break;
      case 4: vpred = QUAD(4); break;  case 5: vpred = QUAD(5); break;
      case 6: vpred = QUAD(6); break;  default: vpred = QUAD(7); break;
    }
    float* lo = out + ((size_t)b * NN + m) * 32 + g * 4;
    float* po = lo + (size_t)NB * NN * 32;
    *reinterpret_cast<f4*>(lo) = vlog;
    *reinterpret_cast<f4*>(po) = vpred;
    return;
  }
  #undef QUAD
  // B update rows g*8..g*8+7 of column m
  int nst = nstar[b * NN + m];
  const f4* BC = reinterpret_cast<const f4*>(Bin + ((size_t)b * NN + m) * 64 + g * 8);
  const f4* BG = reinterpret_cast<const f4*>(Bin + ((size_t)b * NN + nst) * 64 + g * 8);
  f4* BO = reinterpret_cast<f4*>(Bout + ((size_t)b * NN + m) * 64 + g * 8);
  const float invM = 1.0f / 1008.0f;
  bool live = (m < 1008);
  float vv[8];
  #pragma unroll
  for (int jg = 0; jg < 2; jg++) {
    f4 bc4 = BC[jg];
    f4 bg4 = BG[jg];
    f4 vo;
    #pragma unroll
    for (int k = 0; k < 4; k++) {
      int j = g * 8 + jg * 4 + k;
      float v = bc4[k] - bg4[k] * invM;
      #pragma unroll
      for (int cc = 0; cc < 8; cc++) {
        f4 e = es4[j * 8 + ((cc ^ g) & 7)];
        v += e[0]*lg[4*cc] + e[1]*lg[4*cc+1] + e[2]*lg[4*cc+2] + e[3]*lg[4*cc+3];
      }
      vo[k] = v;
      vv[jg * 4 + k] = v;
    }
    BO[jg] = vo;
  }
  // stage masked Bout rows into Cs (reused) for the UpB_next chunk
  #pragma unroll
  for (int jj = 0; jj < 8; jj++)
    Cs[(g * 8 + jj) * 33 + c] = live ? vv[jj] : 0.f;
  __syncthreads();
  float* upb = Upout + ((size_t)(b * 32 + mt)) * 1024;
  for (int idx = t; idx < 1024; idx += 256) {
    int j = idx >> 4, i = idx & 15;
    float s = 0.f;
    #pragma unroll
    for (int cc = 0; cc < 32; cc++) s += Cs[j * 33 + cc] * Xs[i * 33 + cc];
    upb[idx] = s;
  }
}

extern "C" void kernel_launch(void* const* d_in, const int* in_sizes, int n_in,
                              void* d_out, int out_size, void* d_ws, size_t ws_size,
                              hipStream_t stream)
{
  const float* x     = (const float*)d_in[0];
  const float* alpha = (const float*)d_in[1];
  const float* kp    = (const float*)d_in[2];
  const float* emb   = (const float*)d_in[3];
  float* ws = (float*)d_ws;
  float* B0  = ws + OFF_B0;
  float* B1  = ws + OFF_B1;
  float* C   = ws + OFF_C;
  float* UpA = ws + OFF_UPA;
  float* UpB = ws + OFF_UPB;
  float* UpC = ws + OFF_UPC;
  float* Uc  = ws + OFF_UC;
  int*   ns  = (int*)(ws + OFF_NS);
  float* out = (float*)d_out;

  k_init<<<1536, 256, 0, stream>>>(x, emb, B0, UpC, UpA, ns);
  // layer 0: Cin = x[80:144], B0->B1, UpA -> (comb) -> produce UpB
  k_comb<<<128, 256, 0, stream>>>(UpC, UpA, alpha, 0, Uc);
  k_update<<<1024, 256, 0, stream>>>(x, emb, kp, Uc, ns,
                                     x + 80 * NN, (size_t)DINR * NN, C,
                                     B0, B1, UpB, 0, out);
  // layer 1: B1->B0, UpB -> produce UpA
  k_comb<<<128, 256, 0, stream>>>(UpC, UpB, alpha, 1, Uc);
  k_update<<<1024, 256, 0, stream>>>(x, emb, kp, Uc, ns,
                                     C, (size_t)64 * NN, C,
                                     B1, B0, UpA, 0, out);
  // layer 2 (last): outputs only
  k_comb<<<128, 256, 0, stream>>>(UpC, UpA, alpha, 2, Uc);
  k_update<<<1024, 256, 0, stream>>>(x, emb, kp, Uc, ns,
                                     C, (size_t)64 * NN, C,
                                     B0, B1, UpB, 1, out);
}